// Round 3
// baseline (188.280 us; speedup 1.0000x reference)
//
#include <hip/hip_runtime.h>
#include <cstdint>
#include <cstddef>

#define B_  8
#define T_  12
#define N_  250
#define D_  64
#define H_  8
#define HD_ 8
#define WIN_ 3

// ---------------- Kernel A: QKV projection ----------------
__global__ __launch_bounds__(256) void qkv_kernel(
    const float* __restrict__ x,
    const float* __restrict__ Wq, const float* __restrict__ bq,
    const float* __restrict__ Wk, const float* __restrict__ bk,
    const float* __restrict__ Wv, const float* __restrict__ bv,
    float* __restrict__ qb, float* __restrict__ kb, float* __restrict__ vb)
{
    __shared__ float WqT[64*64];
    __shared__ float WkT[64*64];
    __shared__ float WvT[64*64];
    __shared__ float xT[4][64][8];   // per-wave x^T tile: [wave][j][row]

    int tid = threadIdx.x;
    for (int i = tid; i < 4096; i += 256) {
        int d = i >> 6, j = i & 63;
        WqT[j*64 + d] = Wq[i];
        WkT[j*64 + d] = Wk[i];
        WvT[j*64 + d] = Wv[i];
    }
    __syncthreads();

    int wave = tid >> 6, lane = tid & 63;
    int row0 = blockIdx.x * 32 + wave * 8;   // 750*32 = 24000 rows exactly

    #pragma unroll
    for (int rr = 0; rr < 8; ++rr)
        xT[wave][lane][rr] = x[(size_t)(row0 + rr)*64 + lane];

    float accq[8], acck[8], accv[8];
    float bqv = bq[lane], bkv = bk[lane], bvv = bv[lane];
    #pragma unroll
    for (int rr = 0; rr < 8; ++rr) { accq[rr]=bqv; acck[rr]=bkv; accv[rr]=bvv; }

    #pragma unroll 8
    for (int j = 0; j < 64; ++j) {
        float4 xa = *(const float4*)&xT[wave][j][0];
        float4 xb = *(const float4*)&xT[wave][j][4];
        float wq = WqT[j*64 + lane];
        float wk = WkT[j*64 + lane];
        float wv = WvT[j*64 + lane];
        float xr[8] = {xa.x, xa.y, xa.z, xa.w, xb.x, xb.y, xb.z, xb.w};
        #pragma unroll
        for (int rr = 0; rr < 8; ++rr) {
            accq[rr] = fmaf(xr[rr], wq, accq[rr]);
            acck[rr] = fmaf(xr[rr], wk, acck[rr]);
            accv[rr] = fmaf(xr[rr], wv, accv[rr]);
        }
    }

    #pragma unroll
    for (int rr = 0; rr < 8; ++rr) {
        size_t o = (size_t)(row0 + rr)*64 + lane;
        qb[o] = accq[rr];
        kb[o] = acck[rr];
        vb[o] = accv[rr];
    }
}

// ---------------- Kernel T: adj transpose ----------------
__global__ __launch_bounds__(256) void adjT_kernel(
    const float* __restrict__ adj, float* __restrict__ adjT)
{
    __shared__ float tile[32][33];
    int slice = blockIdx.z;
    int tx0 = blockIdx.x * 32, ty0 = blockIdx.y * 32;
    const float* src = adj  + (size_t)slice * 62500;
    float*       dst = adjT + (size_t)slice * 62500;

    int x = tx0 + threadIdx.x;                 // m (contiguous in src row)
    for (int yy = threadIdx.y; yy < 32; yy += 8) {
        int y = ty0 + yy;                      // n
        if (x < 250 && y < 250)
            tile[yy][threadIdx.x] = src[(size_t)y*250 + x];
    }
    __syncthreads();
    int xo = ty0 + threadIdx.x;                // n (contiguous in dst row)
    for (int yy = threadIdx.y; yy < 32; yy += 8) {
        int yo = tx0 + yy;                     // m
        if (xo < 250 && yo < 250)
            dst[(size_t)yo*250 + xo] = tile[threadIdx.x][yy];
    }
}

// ---------------- Kernel B: windowed attention ----------------
// grid = B*T*H*2; which=0 handles ti in {0,1} (shared k/v at t-1, shared raw
// dot); which=1 handles ti=2 (k/v at t). adj values register-prefetched
// 8 m-iterations ahead (16 loads in flight) to cover L3 latency.
__global__ __launch_bounds__(256) void attn_kernel(
    const float* __restrict__ qb, const float* __restrict__ kb,
    const float* __restrict__ vb, const float* __restrict__ adjT,
    float* __restrict__ hs)
{
    __shared__ float4 k4[500];   // 250 rows x 8 floats (head slice)
    __shared__ float4 v4[500];

    int idx = blockIdx.x;
    int which = idx & 1; idx >>= 1;
    int h  = idx % 8; idx /= 8;
    int t  = idx % 12;
    int b  = idx / 12;

    // scales pre-multiplied by log2(e): exp(dr*S) == exp2(dr*Se)
    const float S0e = 0.51010942924719f;     // 8^-0.5 * log2(e)
    const float S1e = 0.18033688011112042f;  // 8^-1   * log2(e)
    const float S2e = 0.06376367865589875f;  // 8^-1.5 * log2(e)

    int t_k = which ? t : (t + 11) % 12;     // k/v time index

    int tid = threadIdx.x;
    const float* kbase = kb + ((size_t)(b*12 + t_k)*250)*64 + h*8;
    const float* vbase = vb + ((size_t)(b*12 + t_k)*250)*64 + h*8;
    for (int i = tid; i < 500; i += 256) {
        int n = i >> 1, half = i & 1;
        k4[i] = *(const float4*)(kbase + (size_t)n*64 + half*4);
        v4[i] = *(const float4*)(vbase + (size_t)n*64 + half*4);
    }
    __syncthreads();

    int n = tid;
    if (n >= 250) return;

    const float* qrow = qb + ((size_t)((b*12 + t)*250) + n)*64 + h*8;
    float4 q0 = *(const float4*)(qrow);
    float4 q1 = *(const float4*)(qrow + 4);

    // scores are tiny (|s| < ~0.3); exp without max-subtract is exact softmax.
    if (which == 0) {
        const float* a0 = adjT + (size_t)(b*12 + (t+11)%12)*62500 + n;
        const float* a1 = adjT + (size_t)(b*12 + t)*62500 + n;
        float pb0[8], pb1[8];
        #pragma unroll
        for (int u = 0; u < 8; ++u) { pb0[u] = a0[u*250]; pb1[u] = a1[u*250]; }

        float Z0 = 0.f, Z1 = 0.f;
        float acc0[8] = {0,0,0,0,0,0,0,0};
        float acc1[8] = {0,0,0,0,0,0,0,0};
        for (int m0 = 0; m0 < 250; m0 += 8) {
            float c0[8], c1[8];
            #pragma unroll
            for (int u = 0; u < 8; ++u) { c0[u] = pb0[u]; c1[u] = pb1[u]; }
            #pragma unroll
            for (int u = 0; u < 8; ++u) {
                int mn = m0 + 8 + u; mn = mn > 249 ? 249 : mn;
                pb0[u] = a0[mn*250]; pb1[u] = a1[mn*250];
            }
            #pragma unroll
            for (int u = 0; u < 8; ++u) {
                int m = m0 + u;
                if (m < 250) {
                    float4 kk0 = k4[2*m], kk1 = k4[2*m + 1];
                    float dr = q0.x*kk0.x + q0.y*kk0.y + q0.z*kk0.z + q0.w*kk0.w
                             + q1.x*kk1.x + q1.y*kk1.y + q1.z*kk1.z + q1.w*kk1.w;
                    float p0 = exp2f(dr*S0e);
                    float p1 = exp2f(dr*S1e);
                    Z0 += p0; Z1 += p1;
                    float pa0 = p0*c0[u], pa1 = p1*c1[u];
                    float4 vv0 = v4[2*m], vv1 = v4[2*m + 1];
                    acc0[0] = fmaf(pa0, vv0.x, acc0[0]); acc1[0] = fmaf(pa1, vv0.x, acc1[0]);
                    acc0[1] = fmaf(pa0, vv0.y, acc0[1]); acc1[1] = fmaf(pa1, vv0.y, acc1[1]);
                    acc0[2] = fmaf(pa0, vv0.z, acc0[2]); acc1[2] = fmaf(pa1, vv0.z, acc1[2]);
                    acc0[3] = fmaf(pa0, vv0.w, acc0[3]); acc1[3] = fmaf(pa1, vv0.w, acc1[3]);
                    acc0[4] = fmaf(pa0, vv1.x, acc0[4]); acc1[4] = fmaf(pa1, vv1.x, acc1[4]);
                    acc0[5] = fmaf(pa0, vv1.y, acc0[5]); acc1[5] = fmaf(pa1, vv1.y, acc1[5]);
                    acc0[6] = fmaf(pa0, vv1.z, acc0[6]); acc1[6] = fmaf(pa1, vv1.z, acc1[6]);
                    acc0[7] = fmaf(pa0, vv1.w, acc0[7]); acc1[7] = fmaf(pa1, vv1.w, acc1[7]);
                }
            }
        }
        float i0 = 1.0f / Z0, i1 = 1.0f / Z1;
        float* o0 = hs + ((size_t)(b*36 + 0*12 + t)*250 + n)*64 + h*8;
        float* o1 = hs + ((size_t)(b*36 + 1*12 + t)*250 + n)*64 + h*8;
        #pragma unroll
        for (int d0 = 0; d0 < 8; ++d0) { o0[d0] = acc0[d0]*i0; o1[d0] = acc1[d0]*i1; }
    } else {
        const float* a2 = adjT + (size_t)(b*12 + (t+1)%12)*62500 + n;
        float pb[8];
        #pragma unroll
        for (int u = 0; u < 8; ++u) pb[u] = a2[u*250];

        float Z = 0.f;
        float acc[8] = {0,0,0,0,0,0,0,0};
        for (int m0 = 0; m0 < 250; m0 += 8) {
            float c[8];
            #pragma unroll
            for (int u = 0; u < 8; ++u) c[u] = pb[u];
            #pragma unroll
            for (int u = 0; u < 8; ++u) {
                int mn = m0 + 8 + u; mn = mn > 249 ? 249 : mn;
                pb[u] = a2[mn*250];
            }
            #pragma unroll
            for (int u = 0; u < 8; ++u) {
                int m = m0 + u;
                if (m < 250) {
                    float4 kk0 = k4[2*m], kk1 = k4[2*m + 1];
                    float dr = q0.x*kk0.x + q0.y*kk0.y + q0.z*kk0.z + q0.w*kk0.w
                             + q1.x*kk1.x + q1.y*kk1.y + q1.z*kk1.z + q1.w*kk1.w;
                    float p = exp2f(dr*S2e);
                    Z += p;
                    float pa = p*c[u];
                    float4 vv0 = v4[2*m], vv1 = v4[2*m + 1];
                    acc[0] = fmaf(pa, vv0.x, acc[0]);
                    acc[1] = fmaf(pa, vv0.y, acc[1]);
                    acc[2] = fmaf(pa, vv0.z, acc[2]);
                    acc[3] = fmaf(pa, vv0.w, acc[3]);
                    acc[4] = fmaf(pa, vv1.x, acc[4]);
                    acc[5] = fmaf(pa, vv1.y, acc[5]);
                    acc[6] = fmaf(pa, vv1.z, acc[6]);
                    acc[7] = fmaf(pa, vv1.w, acc[7]);
                }
            }
        }
        float inv = 1.0f / Z;
        float* o2 = hs + ((size_t)(b*36 + 2*12 + t)*250 + n)*64 + h*8;
        #pragma unroll
        for (int d0 = 0; d0 < 8; ++d0) o2[d0] = acc[d0]*inv;
    }
}

// ---------------- Kernel C: Wd head + residual + LayerNorm ----------------
__global__ __launch_bounds__(256) void out_kernel(
    const float* __restrict__ hsb, const float* __restrict__ x,
    const float* __restrict__ Wd, const float* __restrict__ bd,
    const float* __restrict__ gamma, const float* __restrict__ beta,
    float* __restrict__ out)
{
    __shared__ float hl[36*64];
    __shared__ float xl[12*64];

    int bn = blockIdx.x;
    int n = bn % 250, b = bn / 250;
    int tid = threadIdx.x;

    for (int i = tid; i < 36*64; i += 256) {
        int tw = i >> 6, d = i & 63;
        hl[i] = hsb[((size_t)(b*36 + tw)*250 + n)*64 + d];
    }
    for (int i = tid; i < 12*64; i += 256) {
        int t = i >> 6, d = i & 63;
        xl[i] = x[((size_t)(b*12 + t)*250 + n)*64 + d];
    }
    __syncthreads();

    int lane = tid & 63, wv = tid >> 6;
    float gg = gamma[lane], bb = beta[lane];

    for (int t = wv; t < 12; t += 4) {
        float acc = bd[t];
        const float* wd = Wd + t*36;
        #pragma unroll
        for (int tw = 0; tw < 36; ++tw)
            acc = fmaf(wd[tw], hl[tw*64 + lane], acc);
        float y = acc + xl[t*64 + lane];

        float s = y, s2 = y*y;
        #pragma unroll
        for (int o = 32; o >= 1; o >>= 1) {
            s  += __shfl_xor(s, o);
            s2 += __shfl_xor(s2, o);
        }
        float mu  = s * 0.015625f;
        float var = s2 * 0.015625f - mu*mu;
        out[((size_t)(b*12 + t)*250 + n)*64 + lane] =
            gg * (y - mu) * rsqrtf(var + 1e-5f) + bb;
    }
}

extern "C" void kernel_launch(void* const* d_in, const int* in_sizes, int n_in,
                              void* d_out, int out_size, void* d_ws, size_t ws_size,
                              hipStream_t stream)
{
    const float* x    = (const float*)d_in[0];
    // d_in[1] = ste : unused by the reference
    const float* adj  = (const float*)d_in[2];
    const float* Wq   = (const float*)d_in[3];
    const float* bq   = (const float*)d_in[4];
    const float* Wk   = (const float*)d_in[5];
    const float* bk   = (const float*)d_in[6];
    const float* Wv   = (const float*)d_in[7];
    const float* bv   = (const float*)d_in[8];
    const float* Wd   = (const float*)d_in[9];
    const float* bd   = (const float*)d_in[10];
    const float* gam  = (const float*)d_in[11];
    const float* bet  = (const float*)d_in[12];
    float* out = (float*)d_out;

    float* ws = (float*)d_ws;
    const size_t SZ = (size_t)B_*T_*N_*D_;   // 1,536,000 floats
    float* qb   = ws;
    float* kb   = ws + SZ;
    float* vb   = ws + 2*SZ;
    float* hs   = ws + 3*SZ;                 // 3*SZ floats
    float* adjT = ws + 6*SZ;                 // 6,000,000 floats (24 MB)

    qkv_kernel<<<750, 256, 0, stream>>>(x, Wq, bq, Wk, bk, Wv, bv, qb, kb, vb);
    adjT_kernel<<<dim3(8,8,96), dim3(32,8), 0, stream>>>(adj, adjT);
    attn_kernel<<<B_*T_*H_*2, 256, 0, stream>>>(qb, kb, vb, adjT, hs);
    out_kernel<<<B_*N_, 256, 0, stream>>>(hs, x, Wd, bd, gam, bet, out);
}

// Round 4
// 177.619 us; speedup vs baseline: 1.0600x; 1.0600x over previous
//
#include <hip/hip_runtime.h>
#include <cstdint>
#include <cstddef>

#define B_  8
#define T_  12
#define N_  250
#define D_  64
#define H_  8
#define HD_ 8
#define WIN_ 3

// ---------------- Kernel A: QKV projection ----------------
__global__ __launch_bounds__(256) void qkv_kernel(
    const float* __restrict__ x,
    const float* __restrict__ Wq, const float* __restrict__ bq,
    const float* __restrict__ Wk, const float* __restrict__ bk,
    const float* __restrict__ Wv, const float* __restrict__ bv,
    float* __restrict__ qb, float* __restrict__ kb, float* __restrict__ vb)
{
    __shared__ float WqT[64*64];
    __shared__ float WkT[64*64];
    __shared__ float WvT[64*64];
    __shared__ float xT[4][64][8];   // per-wave x^T tile: [wave][j][row]

    int tid = threadIdx.x;
    for (int i = tid; i < 4096; i += 256) {
        int d = i >> 6, j = i & 63;
        WqT[j*64 + d] = Wq[i];
        WkT[j*64 + d] = Wk[i];
        WvT[j*64 + d] = Wv[i];
    }
    __syncthreads();

    int wave = tid >> 6, lane = tid & 63;
    int row0 = blockIdx.x * 32 + wave * 8;   // 750*32 = 24000 rows exactly

    #pragma unroll
    for (int rr = 0; rr < 8; ++rr)
        xT[wave][lane][rr] = x[(size_t)(row0 + rr)*64 + lane];

    float accq[8], acck[8], accv[8];
    float bqv = bq[lane], bkv = bk[lane], bvv = bv[lane];
    #pragma unroll
    for (int rr = 0; rr < 8; ++rr) { accq[rr]=bqv; acck[rr]=bkv; accv[rr]=bvv; }

    #pragma unroll 8
    for (int j = 0; j < 64; ++j) {
        float4 xa = *(const float4*)&xT[wave][j][0];
        float4 xb = *(const float4*)&xT[wave][j][4];
        float wq = WqT[j*64 + lane];
        float wk = WkT[j*64 + lane];
        float wv = WvT[j*64 + lane];
        float xr[8] = {xa.x, xa.y, xa.z, xa.w, xb.x, xb.y, xb.z, xb.w};
        #pragma unroll
        for (int rr = 0; rr < 8; ++rr) {
            accq[rr] = fmaf(xr[rr], wq, accq[rr]);
            acck[rr] = fmaf(xr[rr], wk, acck[rr]);
            accv[rr] = fmaf(xr[rr], wv, accv[rr]);
        }
    }

    #pragma unroll
    for (int rr = 0; rr < 8; ++rr) {
        size_t o = (size_t)(row0 + rr)*64 + lane;
        qb[o] = accq[rr];
        kb[o] = acck[rr];
        vb[o] = accv[rr];
    }
}

// ---------------- Kernel T: adj transpose ----------------
__global__ __launch_bounds__(256) void adjT_kernel(
    const float* __restrict__ adj, float* __restrict__ adjT)
{
    __shared__ float tile[32][33];
    int slice = blockIdx.z;
    int tx0 = blockIdx.x * 32, ty0 = blockIdx.y * 32;
    const float* src = adj  + (size_t)slice * 62500;
    float*       dst = adjT + (size_t)slice * 62500;

    int x = tx0 + threadIdx.x;                 // m (contiguous in src row)
    for (int yy = threadIdx.y; yy < 32; yy += 8) {
        int y = ty0 + yy;                      // n
        if (x < 250 && y < 250)
            tile[yy][threadIdx.x] = src[(size_t)y*250 + x];
    }
    __syncthreads();
    int xo = ty0 + threadIdx.x;                // n (contiguous in dst row)
    for (int yy = threadIdx.y; yy < 32; yy += 8) {
        int yo = tx0 + yy;                     // m
        if (xo < 250 && yo < 250)
            dst[(size_t)yo*250 + xo] = tile[threadIdx.x][yy];
    }
}

// ---------------- Kernel B: windowed attention ----------------
// grid = B*T*H*2; which=0 handles ti in {0,1} (shared k/v at t-1, shared raw
// dot); which=1 handles ti=2 (k/v at t).
// adj: double-buffered register prefetch (A/B, 8 m each), compile-time
// indices, no clamps. Main loop covers m 0..239; epilogue 240..249. The last
// B-refill overreads up to m=255 (<=6KB past the slice) -- adjT sits at the
// FRONT of ws with >=1MB of slack before qb, so the overread is always
// mapped and the garbage values are never consumed.
__global__ __launch_bounds__(256) void attn_kernel(
    const float* __restrict__ qb, const float* __restrict__ kb,
    const float* __restrict__ vb, const float* __restrict__ adjT,
    float* __restrict__ hs)
{
    __shared__ float4 k4[500];   // 250 rows x 8 floats (head slice)
    __shared__ float4 v4[500];

    int idx = blockIdx.x;
    int which = idx & 1; idx >>= 1;
    int h  = idx % 8; idx /= 8;
    int t  = idx % 12;
    int b  = idx / 12;

    // scales pre-multiplied by log2(e): exp(dr*S) == exp2(dr*Se)
    const float S0e = 0.51010942924719f;     // 8^-0.5 * log2(e)
    const float S1e = 0.18033688011112042f;  // 8^-1   * log2(e)
    const float S2e = 0.06376367865589875f;  // 8^-1.5 * log2(e)

    int t_k = which ? t : (t + 11) % 12;     // k/v time index

    int tid = threadIdx.x;
    const float* kbase = kb + ((size_t)(b*12 + t_k)*250)*64 + h*8;
    const float* vbase = vb + ((size_t)(b*12 + t_k)*250)*64 + h*8;
    for (int i = tid; i < 500; i += 256) {
        int nn = i >> 1, half = i & 1;
        k4[i] = *(const float4*)(kbase + (size_t)nn*64 + half*4);
        v4[i] = *(const float4*)(vbase + (size_t)nn*64 + half*4);
    }
    __syncthreads();

    int n = tid;
    if (n >= 250) return;

    const float* qrow = qb + ((size_t)((b*12 + t)*250) + n)*64 + h*8;
    float4 q0 = *(const float4*)(qrow);
    float4 q1 = *(const float4*)(qrow + 4);

    // scores are tiny (|s| < ~0.3); exp without max-subtract is exact softmax.
    if (which == 0) {
        const float* a0 = adjT + (size_t)(b*12 + (t+11)%12)*62500 + n;
        const float* a1 = adjT + (size_t)(b*12 + t)*62500 + n;

        float A0[8], A1[8], Bb0[8], Bb1[8];
        #pragma unroll
        for (int u = 0; u < 8; ++u) { A0[u]  = a0[u*250];      A1[u]  = a1[u*250]; }
        #pragma unroll
        for (int u = 0; u < 8; ++u) { Bb0[u] = a0[(8+u)*250];  Bb1[u] = a1[(8+u)*250]; }

        float Z0 = 0.f, Z1 = 0.f;
        float acc0[8] = {0,0,0,0,0,0,0,0};
        float acc1[8] = {0,0,0,0,0,0,0,0};

        auto consume = [&](int m, float c0, float c1) {
            float4 kk0 = k4[2*m], kk1 = k4[2*m + 1];
            float dr = q0.x*kk0.x + q0.y*kk0.y + q0.z*kk0.z + q0.w*kk0.w
                     + q1.x*kk1.x + q1.y*kk1.y + q1.z*kk1.z + q1.w*kk1.w;
            float p0 = exp2f(dr*S0e);
            float p1 = exp2f(dr*S1e);
            Z0 += p0; Z1 += p1;
            float pa0 = p0*c0, pa1 = p1*c1;
            float4 vv0 = v4[2*m], vv1 = v4[2*m + 1];
            acc0[0] = fmaf(pa0, vv0.x, acc0[0]); acc1[0] = fmaf(pa1, vv0.x, acc1[0]);
            acc0[1] = fmaf(pa0, vv0.y, acc0[1]); acc1[1] = fmaf(pa1, vv0.y, acc1[1]);
            acc0[2] = fmaf(pa0, vv0.z, acc0[2]); acc1[2] = fmaf(pa1, vv0.z, acc1[2]);
            acc0[3] = fmaf(pa0, vv0.w, acc0[3]); acc1[3] = fmaf(pa1, vv0.w, acc1[3]);
            acc0[4] = fmaf(pa0, vv1.x, acc0[4]); acc1[4] = fmaf(pa1, vv1.x, acc1[4]);
            acc0[5] = fmaf(pa0, vv1.y, acc0[5]); acc1[5] = fmaf(pa1, vv1.y, acc1[5]);
            acc0[6] = fmaf(pa0, vv1.z, acc0[6]); acc1[6] = fmaf(pa1, vv1.z, acc1[6]);
            acc0[7] = fmaf(pa0, vv1.w, acc0[7]); acc1[7] = fmaf(pa1, vv1.w, acc1[7]);
        };

        for (int m0 = 0; m0 < 240; m0 += 16) {
            #pragma unroll
            for (int u = 0; u < 8; ++u) consume(m0 + u, A0[u], A1[u]);
            #pragma unroll
            for (int u = 0; u < 8; ++u) {
                A0[u] = a0[(size_t)(m0+16+u)*250];
                A1[u] = a1[(size_t)(m0+16+u)*250];
            }
            #pragma unroll
            for (int u = 0; u < 8; ++u) consume(m0 + 8 + u, Bb0[u], Bb1[u]);
            #pragma unroll
            for (int u = 0; u < 8; ++u) {
                Bb0[u] = a0[(size_t)(m0+24+u)*250];   // last iter reads to m=255 (pad)
                Bb1[u] = a1[(size_t)(m0+24+u)*250];
            }
        }
        #pragma unroll
        for (int u = 0; u < 8; ++u) consume(240 + u, A0[u], A1[u]);
        consume(248, Bb0[0], Bb1[0]);
        consume(249, Bb0[1], Bb1[1]);

        float i0 = 1.0f / Z0, i1 = 1.0f / Z1;
        float* o0 = hs + ((size_t)(b*36 + 0*12 + t)*250 + n)*64 + h*8;
        float* o1 = hs + ((size_t)(b*36 + 1*12 + t)*250 + n)*64 + h*8;
        #pragma unroll
        for (int d0 = 0; d0 < 8; ++d0) { o0[d0] = acc0[d0]*i0; o1[d0] = acc1[d0]*i1; }
    } else {
        const float* a2 = adjT + (size_t)(b*12 + (t+1)%12)*62500 + n;

        float A[8], Bb[8];
        #pragma unroll
        for (int u = 0; u < 8; ++u) A[u]  = a2[u*250];
        #pragma unroll
        for (int u = 0; u < 8; ++u) Bb[u] = a2[(8+u)*250];

        float Z = 0.f;
        float acc[8] = {0,0,0,0,0,0,0,0};

        auto consume = [&](int m, float c) {
            float4 kk0 = k4[2*m], kk1 = k4[2*m + 1];
            float dr = q0.x*kk0.x + q0.y*kk0.y + q0.z*kk0.z + q0.w*kk0.w
                     + q1.x*kk1.x + q1.y*kk1.y + q1.z*kk1.z + q1.w*kk1.w;
            float p = exp2f(dr*S2e);
            Z += p;
            float pa = p*c;
            float4 vv0 = v4[2*m], vv1 = v4[2*m + 1];
            acc[0] = fmaf(pa, vv0.x, acc[0]);
            acc[1] = fmaf(pa, vv0.y, acc[1]);
            acc[2] = fmaf(pa, vv0.z, acc[2]);
            acc[3] = fmaf(pa, vv0.w, acc[3]);
            acc[4] = fmaf(pa, vv1.x, acc[4]);
            acc[5] = fmaf(pa, vv1.y, acc[5]);
            acc[6] = fmaf(pa, vv1.z, acc[6]);
            acc[7] = fmaf(pa, vv1.w, acc[7]);
        };

        for (int m0 = 0; m0 < 240; m0 += 16) {
            #pragma unroll
            for (int u = 0; u < 8; ++u) consume(m0 + u, A[u]);
            #pragma unroll
            for (int u = 0; u < 8; ++u) A[u] = a2[(size_t)(m0+16+u)*250];
            #pragma unroll
            for (int u = 0; u < 8; ++u) consume(m0 + 8 + u, Bb[u]);
            #pragma unroll
            for (int u = 0; u < 8; ++u) Bb[u] = a2[(size_t)(m0+24+u)*250];
        }
        #pragma unroll
        for (int u = 0; u < 8; ++u) consume(240 + u, A[u]);
        consume(248, Bb[0]);
        consume(249, Bb[1]);

        float inv = 1.0f / Z;
        float* o2 = hs + ((size_t)(b*36 + 2*12 + t)*250 + n)*64 + h*8;
        #pragma unroll
        for (int d0 = 0; d0 < 8; ++d0) o2[d0] = acc[d0]*inv;
    }
}

// ---------------- Kernel C: Wd head + residual + LayerNorm ----------------
__global__ __launch_bounds__(256) void out_kernel(
    const float* __restrict__ hsb, const float* __restrict__ x,
    const float* __restrict__ Wd, const float* __restrict__ bd,
    const float* __restrict__ gamma, const float* __restrict__ beta,
    float* __restrict__ out)
{
    __shared__ float hl[36*64];
    __shared__ float xl[12*64];

    int bn = blockIdx.x;
    int n = bn % 250, b = bn / 250;
    int tid = threadIdx.x;

    for (int i = tid; i < 36*64; i += 256) {
        int tw = i >> 6, d = i & 63;
        hl[i] = hsb[((size_t)(b*36 + tw)*250 + n)*64 + d];
    }
    for (int i = tid; i < 12*64; i += 256) {
        int t = i >> 6, d = i & 63;
        xl[i] = x[((size_t)(b*12 + t)*250 + n)*64 + d];
    }
    __syncthreads();

    int lane = tid & 63, wv = tid >> 6;
    float gg = gamma[lane], bb = beta[lane];

    for (int t = wv; t < 12; t += 4) {
        float acc = bd[t];
        const float* wd = Wd + t*36;
        #pragma unroll
        for (int tw = 0; tw < 36; ++tw)
            acc = fmaf(wd[tw], hl[tw*64 + lane], acc);
        float y = acc + xl[t*64 + lane];

        float s = y, s2 = y*y;
        #pragma unroll
        for (int o = 32; o >= 1; o >>= 1) {
            s  += __shfl_xor(s, o);
            s2 += __shfl_xor(s2, o);
        }
        float mu  = s * 0.015625f;
        float var = s2 * 0.015625f - mu*mu;
        out[((size_t)(b*12 + t)*250 + n)*64 + lane] =
            gg * (y - mu) * rsqrtf(var + 1e-5f) + bb;
    }
}

extern "C" void kernel_launch(void* const* d_in, const int* in_sizes, int n_in,
                              void* d_out, int out_size, void* d_ws, size_t ws_size,
                              hipStream_t stream)
{
    const float* x    = (const float*)d_in[0];
    // d_in[1] = ste : unused by the reference
    const float* adj  = (const float*)d_in[2];
    const float* Wq   = (const float*)d_in[3];
    const float* bq   = (const float*)d_in[4];
    const float* Wk   = (const float*)d_in[5];
    const float* bk   = (const float*)d_in[6];
    const float* Wv   = (const float*)d_in[7];
    const float* bv   = (const float*)d_in[8];
    const float* Wd   = (const float*)d_in[9];
    const float* bd   = (const float*)d_in[10];
    const float* gam  = (const float*)d_in[11];
    const float* bet  = (const float*)d_in[12];
    float* out = (float*)d_out;

    float* ws = (float*)d_ws;
    const size_t SZ = (size_t)B_*T_*N_*D_;   // 1,536,000 floats
    // adjT FIRST (6.0M used, 6.25M reserved -> overread slack), then q/k/v/hs.
    float* adjT = ws;
    float* qb   = ws + 6250000;
    float* kb   = qb + SZ;
    float* vb   = qb + 2*SZ;
    float* hs   = qb + 3*SZ;                 // 3*SZ floats

    qkv_kernel<<<750, 256, 0, stream>>>(x, Wq, bq, Wk, bk, Wv, bv, qb, kb, vb);
    adjT_kernel<<<dim3(8,8,96), dim3(32,8), 0, stream>>>(adj, adjT);
    attn_kernel<<<B_*T_*H_*2, 256, 0, stream>>>(qb, kb, vb, adjT, hs);
    out_kernel<<<B_*N_, 256, 0, stream>>>(hs, x, Wd, bd, gam, bet, out);
}

// Round 5
// 120.292 us; speedup vs baseline: 1.5652x; 1.4766x over previous
//
#include <hip/hip_runtime.h>
#include <cstdint>
#include <cstddef>

#define B_  8
#define T_  12
#define N_  250
#define D_  64
#define H_  8
#define HD_ 8

typedef short     bf16x8  __attribute__((ext_vector_type(8)));
typedef float     f32x16  __attribute__((ext_vector_type(16)));
typedef unsigned  u32x4   __attribute__((ext_vector_type(4)));
typedef float     f32x4u  __attribute__((ext_vector_type(4), aligned(4)));

#if __has_builtin(__builtin_amdgcn_exp2f)
#define EXP2(x) __builtin_amdgcn_exp2f(x)
#else
#define EXP2(x) exp2f(x)
#endif

__device__ __forceinline__ uint16_t f2bf(float f) {
    uint32_t u = __builtin_bit_cast(uint32_t, f);
    uint32_t r = (u + 0x7FFFu + ((u >> 16) & 1u)) >> 16;   // RNE
    return (uint16_t)r;
}

// ---------------- Kernel A: QKV projection -> bf16 operand buffers ----------
// qbh/kbh: [bt*8+h][256 rows (250 used)][8] bf16, row-major 16B rows.
// vbh:     [bt*8+h][8 d][256 m]            bf16 (V transposed per head).
__global__ __launch_bounds__(256) void qkv_kernel(
    const float* __restrict__ x,
    const float* __restrict__ Wq, const float* __restrict__ bq,
    const float* __restrict__ Wk, const float* __restrict__ bk,
    const float* __restrict__ Wv, const float* __restrict__ bv,
    uint16_t* __restrict__ qbh, uint16_t* __restrict__ kbh,
    uint16_t* __restrict__ vbh)
{
    __shared__ float WqT[64*64];
    __shared__ float WkT[64*64];
    __shared__ float WvT[64*64];
    __shared__ float xT[4][64][8];

    int tid = threadIdx.x;
    for (int i = tid; i < 4096; i += 256) {
        int d = i >> 6, j = i & 63;
        WqT[j*64 + d] = Wq[i];
        WkT[j*64 + d] = Wk[i];
        WvT[j*64 + d] = Wv[i];
    }
    __syncthreads();

    int wave = tid >> 6, lane = tid & 63;
    int row0 = blockIdx.x * 32 + wave * 8;   // 750*32 = 24000 rows

    #pragma unroll
    for (int rr = 0; rr < 8; ++rr)
        xT[wave][lane][rr] = x[(size_t)(row0 + rr)*64 + lane];

    float accq[8], acck[8], accv[8];
    float bqv = bq[lane], bkv = bk[lane], bvv = bv[lane];
    #pragma unroll
    for (int rr = 0; rr < 8; ++rr) { accq[rr]=bqv; acck[rr]=bkv; accv[rr]=bvv; }

    #pragma unroll 8
    for (int j = 0; j < 64; ++j) {
        float4 xa = *(const float4*)&xT[wave][j][0];
        float4 xb = *(const float4*)&xT[wave][j][4];
        float wq = WqT[j*64 + lane];
        float wk = WkT[j*64 + lane];
        float wv = WvT[j*64 + lane];
        float xr[8] = {xa.x, xa.y, xa.z, xa.w, xb.x, xb.y, xb.z, xb.w};
        #pragma unroll
        for (int rr = 0; rr < 8; ++rr) {
            accq[rr] = fmaf(xr[rr], wq, accq[rr]);
            acck[rr] = fmaf(xr[rr], wk, acck[rr]);
            accv[rr] = fmaf(xr[rr], wv, accv[rr]);
        }
    }

    int h = lane >> 3, dh = lane & 7;
    #pragma unroll
    for (int rr = 0; rr < 8; ++rr) {
        int row = row0 + rr;
        int bt = row / 250;
        int nn = row - bt*250;
        size_t hb = (size_t)(bt*8 + h);
        qbh[(hb*256 + nn)*8 + dh] = f2bf(accq[rr]);
        kbh[(hb*256 + nn)*8 + dh] = f2bf(acck[rr]);
        vbh[(hb*8 + dh)*256 + nn] = f2bf(accv[rr]);
    }
}

// ---------------- Kernel B: MFMA windowed attention ----------------
// grid = (b,t,h,ti,strip) = 2304*4 blocks x 128 thr (2 waves; wave = n-tile).
// S^T tile via mfma(K,Q): lane holds n=lane&31, m = crow(r,hi) pattern.
// P=exp2(s*scale), Z in-register, P*adj -> cvt_pk_bf16 + permlane32_swap ->
// PV B-operand; PV = mfma(V^T, P^T) keeps n=lane&31 for direct Z-normalize.
__global__ __launch_bounds__(128) void attn_kernel(
    const uint16_t* __restrict__ qbh, const uint16_t* __restrict__ kbh,
    const uint16_t* __restrict__ vbh, const float* __restrict__ adj,
    float* __restrict__ hs)
{
    const float S0e = 0.51006972338f;    // 8^-0.5 * log2(e)
    const float S1e = 0.18033688011f;    // 8^-1   * log2(e)
    const float S2e = 0.06375872168f;    // 8^-1.5 * log2(e)

    int tid  = threadIdx.x;
    int nt   = tid >> 6;          // wave id = n-tile within strip
    int lane = tid & 63;
    int ln31 = lane & 31, hi = lane >> 5;

    int idx = blockIdx.x;
    int strip = idx & 3; idx >>= 2;
    int ti = idx % 3; idx /= 3;
    int h  = idx & 7; idx >>= 3;
    int t  = idx % 12;
    int b  = idx / 12;

    int t_k = (ti == 2) ? t : (t + 11) % 12;   // cumulative k/v shift
    int t_a = (t + ti + 11) % 12;              // fresh adj shift
    float scale = (ti == 0) ? S0e : (ti == 1) ? S1e : S2e;

    const uint16_t* qh = qbh + ((size_t)((b*12 + t  )*8 + h) * 256) * 8;
    const uint16_t* kh = kbh + ((size_t)((b*12 + t_k)*8 + h) * 256) * 8;
    const uint16_t* vh = vbh + ((size_t)((b*12 + t_k)*8 + h) * 8) * 256;
    const float* adj_s = adj + (size_t)(b*12 + t_a) * 62500;

    int n0 = strip*64 + nt*32;
    int n  = n0 + ln31;
    int nc = n > 249 ? 249 : n;

    // Q B-frag: col n, k=d (hi half -> k 8..15 unused, zero)
    bf16x8 qf = *(const bf16x8*)(qh + (size_t)n * 8);
    bf16x8 z8 = {0,0,0,0,0,0,0,0};
    if (hi) qf = z8;

    const float* arow = adj_s + (size_t)nc * 250;

    f32x16 acc, zc;
    #pragma unroll
    for (int i = 0; i < 16; ++i) { acc[i] = 0.f; zc[i] = 0.f; }
    float z = 0.f;
    int vrow = ln31 & 7;
    bool vzero = (ln31 >= 8);

    #pragma unroll
    for (int mt = 0; mt < 8; ++mt) {
        int m0 = mt * 32;
        // A-frag K: row m, k=d (hi half zero)
        bf16x8 kf = *(const bf16x8*)(kh + (size_t)(m0 + ln31) * 8);
        if (hi) kf = z8;
        f32x16 s = __builtin_amdgcn_mfma_f32_32x32x16_bf16(kf, qf, zc, 0, 0, 0);

        // adj gather: m-offsets {0,8,16,24}+4*hi, 4 consecutive each
        f32x4u a0 = *(const f32x4u*)(arow + m0 +      4*hi);
        f32x4u a1 = *(const f32x4u*)(arow + m0 +  8 + 4*hi);
        f32x4u a2 = *(const f32x4u*)(arow + m0 + 16 + 4*hi);
        f32x4u a3 = *(const f32x4u*)(arow + m0 + 24 + 4*hi);

        float pa[16];
        #pragma unroll
        for (int r = 0; r < 16; ++r) {
            float p = EXP2(s[r] * scale);
            if (mt == 7) {
                int crow = (r & 3) + 8*(r >> 2) + 4*hi;
                p = (224 + crow < 250) ? p : 0.f;   // mask m-pad 250..255
            }
            z += p;
            float av = (r < 4) ? a0[r & 3] : (r < 8) ? a1[r & 3]
                     : (r < 12) ? a2[r & 3] : a3[r & 3];
            pa[r] = p * av;
        }

        // pack pairs to bf16 words; w[e] covers m-offsets {2e,2e+1} of crow set
        unsigned w[8];
        #pragma unroll
        for (int e = 0; e < 8; ++e)
            asm("v_cvt_pk_bf16_f32 %0, %1, %2"
                : "=v"(w[e]) : "v"(pa[2*e]), "v"(pa[2*e+1]));
        // half-swaps: after these, (w0..w3) = P^T k 0..15, (w4..w7) = k 16..31
        asm volatile("v_permlane32_swap_b32 %0, %1" : "+v"(w[2]), "+v"(w[0]));
        asm volatile("v_permlane32_swap_b32 %0, %1" : "+v"(w[3]), "+v"(w[1]));
        asm volatile("v_permlane32_swap_b32 %0, %1" : "+v"(w[6]), "+v"(w[4]));
        asm volatile("v_permlane32_swap_b32 %0, %1" : "+v"(w[7]), "+v"(w[5]));

        u32x4 t1 = {w[0], w[1], w[2], w[3]};
        u32x4 t2 = {w[4], w[5], w[6], w[7]};
        bf16x8 pf1 = __builtin_bit_cast(bf16x8, t1);
        bf16x8 pf2 = __builtin_bit_cast(bf16x8, t2);

        // V^T A-frags: row d=ln31 (>=8 zero), k = m-offset
        bf16x8 vf1 = *(const bf16x8*)(vh + (size_t)vrow*256 + m0 + hi*8);
        bf16x8 vf2 = *(const bf16x8*)(vh + (size_t)vrow*256 + m0 + 16 + hi*8);
        if (vzero) { vf1 = z8; vf2 = z8; }

        acc = __builtin_amdgcn_mfma_f32_32x32x16_bf16(vf1, pf1, acc, 0, 0, 0);
        acc = __builtin_amdgcn_mfma_f32_32x32x16_bf16(vf2, pf2, acc, 0, 0, 0);
    }

    float zf = z + __shfl_xor(z, 32);
    float inv = 1.0f / zf;

    if (n < 250) {
        float4 o;
        o.x = acc[0] * inv; o.y = acc[1] * inv;
        o.z = acc[2] * inv; o.w = acc[3] * inv;
        *(float4*)(hs + (((size_t)(b*36 + ti*12 + t)*250 + n)*64 + h*8 + hi*4)) = o;
    }
}

// ---------------- Kernel C: Wd head + residual + LayerNorm ----------------
__global__ __launch_bounds__(256) void out_kernel(
    const float* __restrict__ hsb, const float* __restrict__ x,
    const float* __restrict__ Wd, const float* __restrict__ bd,
    const float* __restrict__ gamma, const float* __restrict__ beta,
    float* __restrict__ out)
{
    __shared__ float hl[36*64];
    __shared__ float xl[12*64];

    int bn = blockIdx.x;
    int n = bn % 250, b = bn / 250;
    int tid = threadIdx.x;

    for (int i = tid; i < 36*64; i += 256) {
        int tw = i >> 6, d = i & 63;
        hl[i] = hsb[((size_t)(b*36 + tw)*250 + n)*64 + d];
    }
    for (int i = tid; i < 12*64; i += 256) {
        int t = i >> 6, d = i & 63;
        xl[i] = x[((size_t)(b*12 + t)*250 + n)*64 + d];
    }
    __syncthreads();

    int lane = tid & 63, wv = tid >> 6;
    float gg = gamma[lane], bb = beta[lane];

    for (int t = wv; t < 12; t += 4) {
        float acc = bd[t];
        const float* wd = Wd + t*36;
        #pragma unroll
        for (int tw = 0; tw < 36; ++tw)
            acc = fmaf(wd[tw], hl[tw*64 + lane], acc);
        float y = acc + xl[t*64 + lane];

        float s = y, s2 = y*y;
        #pragma unroll
        for (int o = 32; o >= 1; o >>= 1) {
            s  += __shfl_xor(s, o);
            s2 += __shfl_xor(s2, o);
        }
        float mu  = s * 0.015625f;
        float var = s2 * 0.015625f - mu*mu;
        out[((size_t)(b*12 + t)*250 + n)*64 + lane] =
            gg * (y - mu) * rsqrtf(var + 1e-5f) + bb;
    }
}

extern "C" void kernel_launch(void* const* d_in, const int* in_sizes, int n_in,
                              void* d_out, int out_size, void* d_ws, size_t ws_size,
                              hipStream_t stream)
{
    const float* x    = (const float*)d_in[0];
    // d_in[1] = ste : unused by the reference
    const float* adj  = (const float*)d_in[2];
    const float* Wq   = (const float*)d_in[3];
    const float* bq   = (const float*)d_in[4];
    const float* Wk   = (const float*)d_in[5];
    const float* bk   = (const float*)d_in[6];
    const float* Wv   = (const float*)d_in[7];
    const float* bv   = (const float*)d_in[8];
    const float* Wd   = (const float*)d_in[9];
    const float* bd   = (const float*)d_in[10];
    const float* gam  = (const float*)d_in[11];
    const float* bet  = (const float*)d_in[12];
    float* out = (float*)d_out;

    // ws layout (bytes): hs f32 [4,608,000] | qbh | kbh | vbh (bf16, each
    // 96*8 heads * 2048 elems = 3,145,728 B). Pad-row overreads from attn
    // stay inside ws (tail slack far below ws_size used in prior rounds).
    float*    hs  = (float*)d_ws;
    uint16_t* qbh = (uint16_t*)((char*)d_ws + 18432000);
    uint16_t* kbh = qbh + 1572864;
    uint16_t* vbh = kbh + 1572864;

    qkv_kernel<<<750, 256, 0, stream>>>(x, Wq, bq, Wk, bk, Wv, bv, qbh, kbh, vbh);
    attn_kernel<<<B_*T_*H_*3*4, 128, 0, stream>>>(qbh, kbh, vbh, adj, hs);
    out_kernel<<<B_*N_, 256, 0, stream>>>(hs, x, Wd, bd, gam, bet, out);
}